// Round 13
// baseline (639.827 us; speedup 1.0000x reference)
//
#include <hip/hip_runtime.h>

typedef float    f32x4  __attribute__((ext_vector_type(4)));
typedef float    f32x16 __attribute__((ext_vector_type(16)));
typedef _Float16 f16x4  __attribute__((ext_vector_type(4)));
typedef _Float16 f16x8  __attribute__((ext_vector_type(8)));

#define N_IMG 50000
#define NPAD  50176       // imgh padded rows (zeros beyond 50000)
#define BROWS 256
#define CHW   3072
#define BK    64
#define BM    128
#define BN    128
#define EHS   50176       // padded k stride for eh (zeros beyond 50000)
#define KCHUNK 3136       // 49*64 split-K chunk for GEMM2 (16*3136 = 50176)
#define NSPLIT 16

// direct global->LDS (wave-uniform LDS base + lane*16B; per-lane global addr)
__device__ __forceinline__ void glds16(const void* g, void* l) {
    __builtin_amdgcn_global_load_lds(
        (const __attribute__((address_space(1))) void*)g,
        (__attribute__((address_space(3))) void*)l, 16, 0, 0);
}

// ---------------- scalars from t ----------------
__global__ void k_scalars(const float* __restrict__ t, float* __restrict__ sc) {
    if (threadIdx.x == 0) {
        double tv  = (double)t[0];
        double ang = tv * (1.5707963267948966 / 1.008);
        double c   = cos(ang);
        double at  = c;
        double bt2 = 1.0 - c * c;
        sc[0] = (float)at;
        sc[1] = (float)bt2;
        sc[2] = (float)(at / bt2);             // c_cross
        sc[3] = (float)(at * at * 0.5 / bt2);  // c_y2
        sc[4] = (float)(1.0 / bt2);            // inv_bt2
    }
}

// ---------------- x -> f16 ----------------
// -||x||^2 logit term is a per-row constant -> cancelled by row softmax; omitted.
__global__ void k_xprep(const float* __restrict__ x, _Float16* __restrict__ xh) {
    int idx = blockIdx.x * 256 + threadIdx.x;
    f32x4 v = ((const f32x4*)x)[idx];
    f16x4 h;
    h[0] = (_Float16)v[0]; h[1] = (_Float16)v[1];
    h[2] = (_Float16)v[2]; h[3] = (_Float16)v[3];
    ((f16x4*)xh)[idx] = h;
}

// ---------------- img -> f16 [n][d] + y2 (row per block; proven ~150us) ----------
// Rows >= N_IMG written as zeros (NaN-safe padding for GEMM2's K tail).
__global__ void k_prep(const float* __restrict__ img, _Float16* __restrict__ imgh,
                       float* __restrict__ y2) {
    int row = blockIdx.x, tid = threadIdx.x;
    f16x4* dst = (f16x4*)(imgh + (size_t)row * CHW);
    if (row >= N_IMG) {
        f16x4 z = {(_Float16)0.f, (_Float16)0.f, (_Float16)0.f, (_Float16)0.f};
        #pragma unroll
        for (int i = 0; i < 3; i++) dst[tid + i * 256] = z;
        return;
    }
    const f32x4* src = (const f32x4*)(img + (size_t)row * CHW);
    float s = 0.f;
    #pragma unroll
    for (int i = 0; i < 3; i++) {
        f32x4 v = src[tid + i * 256];
        s += v[0]*v[0] + v[1]*v[1] + v[2]*v[2] + v[3]*v[3];
        f16x4 h;
        h[0] = (_Float16)v[0]; h[1] = (_Float16)v[1];
        h[2] = (_Float16)v[2]; h[3] = (_Float16)v[3];
        dst[tid + i * 256] = h;
    }
    for (int o = 32; o > 0; o >>= 1) s += __shfl_down(s, o);
    __shared__ float wsum[4];
    if ((tid & 63) == 0) wsum[tid >> 6] = s;
    __syncthreads();
    if (tid == 0) y2[row] = (wsum[0] + wsum[1]) + (wsum[2] + wsum[3]);
}

// ---------------- GEMM1: logits = c_cross*(xh@imghT) - c_y2*y2 ----------------
// v5: B via glds (proven m97 path); A-fragments DIRECT FROM GLOBAL (xh is
// 1.5MB, L2-resident per XCD) -> Alds deleted, 8 ds_read/iter removed.
__global__ __launch_bounds__(256, 3) void k_gemm1(
        const _Float16* __restrict__ xh, const _Float16* __restrict__ imgh,
        const float* __restrict__ y2g, const float* __restrict__ sc,
        float* __restrict__ logits) {
    __shared__ _Float16 Blds[BN * BK];   // 16 KB, [row][g^(row&7)] 16B granules

    const int tid = threadIdx.x;
    const int wid = tid >> 6, lane = tid & 63;
    const int flat = blockIdx.x;          // 0..783
    const int xcd = flat & 7, loc = flat >> 3;          // loc 0..97
    const int m0 = (loc & 1) * BM;
    const int n0 = (xcd * 49 + (loc >> 1)) * BN;

    const _Float16* gB[4]; _Float16* lB[4];
    #pragma unroll
    for (int j = 0; j < 4; j++) {
        int seg = wid * 4 + j;
        int row = seg * 8 + (lane >> 3);
        int off = (((lane & 7) ^ (row & 7)) << 3);   // f16 elements
        gB[j] = imgh + (size_t)(n0 + row) * CHW + off;   // n0+row < NPAD (zero pad)
        lB[j] = Blds + seg * 512;
    }

    const int wm = wid >> 1, wn = wid & 1;
    const int rm = wm * 64, cn = wn * 64;
    const int lr = lane & 31, hi = lane >> 5;
    const int xm = (lr & 7) << 4;                    // read-side byte XOR
    const char* Bb = (const char*)Blds;
    const int br0 = (cn + lr) * 128,      br1 = (cn + 32 + lr) * 128;
    const int kof = hi * 16;

    // A-fragment global bases: frag = xh[m0+rm(+32)+lr][it*64 + ks*16 + hi*8 ..+8]
    const _Float16* aB0 = xh + (size_t)(m0 + rm + lr) * CHW + hi * 8;
    const _Float16* aB1 = xh + (size_t)(m0 + rm + 32 + lr) * CHW + hi * 8;

    f32x16 acc[2][2];
    #pragma unroll
    for (int mi = 0; mi < 2; mi++)
        #pragma unroll
        for (int ni = 0; ni < 2; ni++)
            #pragma unroll
            for (int r = 0; r < 16; r++) acc[mi][ni][r] = 0.f;

    for (int it = 0; it < CHW / BK; ++it) {
        if (it) __syncthreads();
        #pragma unroll
        for (int j = 0; j < 4; j++) glds16(gB[j] + it * BK, lB[j]);
        f16x8 a0[4], a1[4];
        #pragma unroll
        for (int ks = 0; ks < 4; ++ks) {          // L2-hot global loads
            a0[ks] = *(const f16x8*)(aB0 + it * BK + ks * 16);
            a1[ks] = *(const f16x8*)(aB1 + it * BK + ks * 16);
        }
        __syncthreads();
        #pragma unroll
        for (int ks = 0; ks < 4; ++ks) {
            int off = (ks * 32 + kof) ^ xm;
            f16x8 b0 = *(const f16x8*)(Bb + br0 + off);
            f16x8 b1 = *(const f16x8*)(Bb + br1 + off);
            acc[0][0] = __builtin_amdgcn_mfma_f32_32x32x16_f16(a0[ks], b0, acc[0][0], 0, 0, 0);
            acc[0][1] = __builtin_amdgcn_mfma_f32_32x32x16_f16(a0[ks], b1, acc[0][1], 0, 0, 0);
            acc[1][0] = __builtin_amdgcn_mfma_f32_32x32x16_f16(a1[ks], b0, acc[1][0], 0, 0, 0);
            acc[1][1] = __builtin_amdgcn_mfma_f32_32x32x16_f16(a1[ks], b1, acc[1][1], 0, 0, 0);
        }
    }

    const float c_cross = sc[2], c_y2 = sc[3];
    #pragma unroll
    for (int mi = 0; mi < 2; mi++)
        #pragma unroll
        for (int ni = 0; ni < 2; ni++) {
            int col = n0 + cn + ni * 32 + lr;
            if (col >= N_IMG) continue;
            float y2v = y2g[col];
            f32x16 v = acc[mi][ni];
            #pragma unroll
            for (int r = 0; r < 16; r++) {
                int row = m0 + rm + mi * 32 + (r & 3) + 8 * (r >> 2) + 4 * hi;
                logits[(size_t)row * N_IMG + col] = c_cross * v[r] - c_y2 * y2v;
            }
        }
}

// ---------------- fused row max + exp + row sum (writes padded eh) ----------------
__global__ void k_softmax(const float* __restrict__ logits, _Float16* __restrict__ eh,
                          float* __restrict__ rowsum) {
    int row = blockIdx.x, tid = threadIdx.x;
    const f32x4* lr = (const f32x4*)(logits + (size_t)row * N_IMG);
    _Float16* erow = eh + (size_t)row * EHS;
    f16x4* er = (f16x4*)erow;
    __shared__ float wred[4];

    if (tid < EHS - N_IMG) erow[N_IMG + tid] = (_Float16)0.f;   // zero K-tail pad

    float m = -3.0e38f;
    for (int i = tid; i < N_IMG / 4; i += 256) {
        f32x4 v = lr[i];
        m = fmaxf(m, fmaxf(fmaxf(v[0], v[1]), fmaxf(v[2], v[3])));
    }
    for (int o = 32; o > 0; o >>= 1) m = fmaxf(m, __shfl_down(m, o));
    if ((tid & 63) == 0) wred[tid >> 6] = m;
    __syncthreads();
    m = fmaxf(fmaxf(wred[0], wred[1]), fmaxf(wred[2], wred[3]));
    __syncthreads();

    float s = 0.f;
    for (int i = tid; i < N_IMG / 4; i += 256) {
        f32x4 v = lr[i];
        float e0 = __expf(v[0] - m), e1 = __expf(v[1] - m);
        float e2 = __expf(v[2] - m), e3 = __expf(v[3] - m);
        s += (e0 + e1) + (e2 + e3);
        f16x4 h;
        h[0] = (_Float16)e0; h[1] = (_Float16)e1;
        h[2] = (_Float16)e2; h[3] = (_Float16)e3;
        er[i] = h;
    }
    for (int o = 32; o > 0; o >>= 1) s += __shfl_down(s, o);
    if ((tid & 63) == 0) wred[tid >> 6] = s;
    __syncthreads();
    if (tid == 0) rowsum[row] = (wred[0] + wred[1]) + (wred[2] + wred[3]);
}

// ---------------- GEMM2: partial[ck] = eh[:,chunk] @ imgh[chunk,:] ----------------
// v5: in-LDS transpose (proven R10/R11) + A-fragments DIRECT FROM GLOBAL
// (eh chunk 0.8MB, L2-hot across the 24 same-XCD d-blocks). Alds deleted:
// ds-instr/iter 28 -> 20. LDS 32KB.
__global__ __launch_bounds__(256, 3) void k_gemm2(
        const _Float16* __restrict__ eh, const _Float16* __restrict__ imgh,
        float* __restrict__ partial) {
    __shared__ _Float16 Blds[BN * BK];     // 16 KB, [d][k] swizzled granules
    __shared__ _Float16 Tmp[BK * BN];      // 16 KB, [k][d] linear

    const int tid = threadIdx.x;
    const int wid = tid >> 6, lane = tid & 63;
    const int flat = blockIdx.x;          // 0..767
    const int xcd = flat & 7, loc = flat >> 3;          // loc 0..95
    const int ck  = xcd * 2 + (loc >= 48 ? 1 : 0);
    const int rem = loc - (loc >= 48 ? 48 : 0);         // 0..47
    const int m0 = (rem & 1) * BM;
    const int d0 = (rem >> 1) * BN;
    const int kbase = ck * KCHUNK;
    const int ITERS = KCHUNK / BK;        // 49

    const _Float16* gB[4]; _Float16* lB[4];
    #pragma unroll
    for (int j = 0; j < 4; j++) {
        int seg = wid * 4 + j;                         // 0..15
        gB[j] = imgh + (size_t)(kbase + seg * 4 + (lane >> 4)) * CHW + d0 + (lane & 15) * 8;
        lB[j] = Tmp + seg * 512;
    }

    const int q   = tid & 31;             // d-quad 0..31
    const int oct = tid >> 5;             // k-octet 0..7

    const int wm = wid >> 1, wn = wid & 1;
    const int rm = wm * 64, cn = wn * 64;
    const int lr = lane & 31, hi = lane >> 5;
    const int xm = (lr & 7) << 4;
    const int br0 = (cn + lr) * 128, br1 = (cn + 32 + lr) * 128;
    const int kof = hi * 16;
    const char* Bb = (const char*)Blds;

    // A-fragment global bases: frag = eh[m0+rm(+32)+lr][kbase + it*64 + ks*16 + hi*8]
    const _Float16* aB0 = eh + (size_t)(m0 + rm + lr) * EHS + kbase + hi * 8;
    const _Float16* aB1 = eh + (size_t)(m0 + rm + 32 + lr) * EHS + kbase + hi * 8;

    f32x16 acc[2][2];
    #pragma unroll
    for (int mi = 0; mi < 2; mi++)
        #pragma unroll
        for (int ni = 0; ni < 2; ni++)
            #pragma unroll
            for (int r = 0; r < 16; r++) acc[mi][ni][r] = 0.f;

    // prologue: stage it=0 into Tmp
    #pragma unroll
    for (int j = 0; j < 4; j++) glds16(gB[j], lB[j]);

    for (int it = 0; it < ITERS; ++it) {
        __syncthreads();   // Tmp(it) landed; Blds(it-1) consumed

        // A-fragments from global (L2-hot), overlapping the transpose below
        f16x8 afr0[4], afr1[4];
        #pragma unroll
        for (int ks = 0; ks < 4; ++ks) {
            afr0[ks] = *(const f16x8*)(aB0 + it * BK + ks * 16);
            afr1[ks] = *(const f16x8*)(aB1 + it * BK + ks * 16);
        }
        // transpose Tmp[k][d] -> Blds[d][k] (swizzled)
        {
            f16x4 r[8];
            #pragma unroll
            for (int j = 0; j < 8; j++)
                r[j] = *(const f16x4*)&Tmp[(oct * 8 + j) * 128 + q * 4];
            #pragma unroll
            for (int dd = 0; dd < 4; dd++) {
                f16x8 w;
                #pragma unroll
                for (int j = 0; j < 8; j++) w[j] = r[j][dd];
                int d = q * 4 + dd;
                *(f16x8*)((char*)Blds + d * 128 + ((oct ^ (d & 7)) << 4)) = w;
            }
        }
        __syncthreads();   // Blds ready; Tmp free

        if (it + 1 < ITERS) {
            #pragma unroll
            for (int j = 0; j < 4; j++) glds16(gB[j] + (size_t)(it + 1) * BK * CHW, lB[j]);
        }
        #pragma unroll
        for (int ks = 0; ks < 4; ++ks) {
            int offb = (ks * 32 + kof) ^ xm;
            f16x8 b0 = *(const f16x8*)(Bb + br0 + offb);
            f16x8 b1 = *(const f16x8*)(Bb + br1 + offb);
            acc[0][0] = __builtin_amdgcn_mfma_f32_32x32x16_f16(afr0[ks], b0, acc[0][0], 0, 0, 0);
            acc[0][1] = __builtin_amdgcn_mfma_f32_32x32x16_f16(afr0[ks], b1, acc[0][1], 0, 0, 0);
            acc[1][0] = __builtin_amdgcn_mfma_f32_32x32x16_f16(afr1[ks], b0, acc[1][0], 0, 0, 0);
            acc[1][1] = __builtin_amdgcn_mfma_f32_32x32x16_f16(afr1[ks], b1, acc[1][1], 0, 0, 0);
        }
    }

    float* pp = partial + (size_t)ck * BROWS * CHW;
    #pragma unroll
    for (int mi = 0; mi < 2; mi++)
        #pragma unroll
        for (int ni = 0; ni < 2; ni++) {
            int dcol = d0 + cn + ni * 32 + lr;
            f32x16 v = acc[mi][ni];
            #pragma unroll
            for (int r = 0; r < 16; r++) {
                int row = m0 + rm + mi * 32 + (r & 3) + 8 * (r >> 2) + 4 * hi;
                pp[(size_t)row * CHW + dcol] = v[r];
            }
        }
}

// ---------------- reduce partials + final score ----------------
__global__ void k_final(const float* __restrict__ partial, const float* __restrict__ x,
                        const float* __restrict__ rowsum, const float* __restrict__ sc,
                        float* __restrict__ out) {
    int idx = blockIdx.x * 256 + threadIdx.x;
    int row = idx / (CHW / 4);
    float at = sc[0], invbt2 = sc[4];
    float scale = at * invbt2 / rowsum[row];
    const f32x4* p4 = (const f32x4*)partial;
    f32x4 s = p4[idx];
    #pragma unroll
    for (int c = 1; c < NSPLIT; c++) s = s + p4[(size_t)c * (BROWS * CHW / 4) + idx];
    f32x4 xv = ((const f32x4*)x)[idx];
    f32x4 o;
    #pragma unroll
    for (int j = 0; j < 4; j++) o[j] = s[j] * scale - xv[j] * invbt2;
    ((f32x4*)out)[idx] = o;
}

extern "C" void kernel_launch(void* const* d_in, const int* in_sizes, int n_in,
                              void* d_out, int out_size, void* d_ws, size_t ws_size,
                              hipStream_t stream) {
    const float* t   = (const float*)d_in[0];
    const float* x   = (const float*)d_in[1];
    const float* img = (const float*)d_in[2];
    float* out = (float*)d_out;
    char* ws = (char*)d_ws;

    // ws layout (bytes)
    float*    sc     = (float*)(ws + 0);                   // 64 B
    float*    rowsum = (float*)(ws + 256);                 // 1 KB
    float*    y2     = (float*)(ws + 4096);                // 200 KB
    _Float16* xh     = (_Float16*)(ws + 212992);           // 1.5 MB
    _Float16* imgh   = (_Float16*)(ws + 2097152);          // 308.3 MB [NPAD][CHW]
    _Float16* eh     = (_Float16*)(ws + 310378496);        // 25.7 MB  [b][EHS]
    float*    logits = (float*)(ws + 336068608);           // 51.2 MB
    float*    partial = logits;                            // reused (50.4 MB)

    k_scalars<<<1, 64, 0, stream>>>(t, sc);
    k_xprep<<<(BROWS * CHW / 4) / 256, 256, 0, stream>>>(x, xh);
    k_prep<<<NPAD, 256, 0, stream>>>(img, imgh, y2);
    k_gemm1<<<784, 256, 0, stream>>>(xh, imgh, y2, sc, logits);
    k_softmax<<<256, 256, 0, stream>>>(logits, eh, rowsum);
    k_gemm2<<<768, 256, 0, stream>>>(eh, imgh, partial);
    k_final<<<(BROWS * CHW / 4) / 256, 256, 0, stream>>>(partial, x, rowsum, sc, out);
}

// Round 14
// 494.253 us; speedup vs baseline: 1.2945x; 1.2945x over previous
//
#include <hip/hip_runtime.h>

typedef float    f32x4  __attribute__((ext_vector_type(4)));
typedef float    f32x16 __attribute__((ext_vector_type(16)));
typedef _Float16 f16x4  __attribute__((ext_vector_type(4)));
typedef _Float16 f16x8  __attribute__((ext_vector_type(8)));

#define N_IMG 50000
#define NPAD  50176       // imgh padded rows (zeros beyond 50000)
#define BROWS 256
#define CHW   3072
#define BK    64
#define BM    128
#define BN    128
#define KCHUNK 3136       // 49*64 split-K chunk for GEMM2 (16*3136 = 50176)
#define NSPLIT 16
#define XG    384         // granules per row in xhf (3072/8)
#define EG    6272        // granules per row in ehf (50176/8)

// direct global->LDS (wave-uniform LDS base + lane*16B; per-lane global addr)
__device__ __forceinline__ void glds16(const void* g, void* l) {
    __builtin_amdgcn_global_load_lds(
        (const __attribute__((address_space(1))) void*)g,
        (__attribute__((address_space(3))) void*)l, 16, 0, 0);
}

// ---------------- scalars from t ----------------
__global__ void k_scalars(const float* __restrict__ t, float* __restrict__ sc) {
    if (threadIdx.x == 0) {
        double tv  = (double)t[0];
        double ang = tv * (1.5707963267948966 / 1.008);
        double c   = cos(ang);
        double at  = c;
        double bt2 = 1.0 - c * c;
        sc[0] = (float)at;
        sc[1] = (float)bt2;
        sc[2] = (float)(at / bt2);             // c_cross
        sc[3] = (float)(at * at * 0.5 / bt2);  // c_y2
        sc[4] = (float)(1.0 / bt2);            // inv_bt2
    }
}

// ---------------- x -> f16 in MFMA-fragment layout ----------------
// xhf elem addr: ((rowgrp*XG + gi)*32 + lr)*8, rowgrp=row>>5, lr=row&31,
// gi = k>>3. A wave's fragment load = lane-consecutive 16B (coalesced).
// -||x||^2 logit term is a per-row constant -> cancelled by row softmax; omitted.
__global__ void k_xprep(const float* __restrict__ x, _Float16* __restrict__ xhf) {
    int row = blockIdx.x, t = threadIdx.x;      // 128 threads
    int rowgrp = row >> 5, lr = row & 31;
    _Float16* base = xhf + ((size_t)rowgrp * XG * 32 + lr) * 8;
    #pragma unroll
    for (int j = 0; j < 3; j++) {
        int g = t + j * 128;                    // 0..383
        const f32x4* s = (const f32x4*)(x + (size_t)row * CHW + g * 8);
        f32x4 a = s[0], b = s[1];
        f16x8 h;
        #pragma unroll
        for (int q = 0; q < 4; q++) { h[q] = (_Float16)a[q]; h[4+q] = (_Float16)b[q]; }
        *(f16x8*)(base + (size_t)g * 256) = h;
    }
}

// ---------------- img -> f16 [n][d] + y2 (row per block; proven ~150us) ----------
// Rows >= N_IMG written as zeros (NaN-safe padding for GEMM2's K tail).
__global__ void k_prep(const float* __restrict__ img, _Float16* __restrict__ imgh,
                       float* __restrict__ y2) {
    int row = blockIdx.x, tid = threadIdx.x;
    f16x4* dst = (f16x4*)(imgh + (size_t)row * CHW);
    if (row >= N_IMG) {
        f16x4 z = {(_Float16)0.f, (_Float16)0.f, (_Float16)0.f, (_Float16)0.f};
        #pragma unroll
        for (int i = 0; i < 3; i++) dst[tid + i * 256] = z;
        return;
    }
    const f32x4* src = (const f32x4*)(img + (size_t)row * CHW);
    float s = 0.f;
    #pragma unroll
    for (int i = 0; i < 3; i++) {
        f32x4 v = src[tid + i * 256];
        s += v[0]*v[0] + v[1]*v[1] + v[2]*v[2] + v[3]*v[3];
        f16x4 h;
        h[0] = (_Float16)v[0]; h[1] = (_Float16)v[1];
        h[2] = (_Float16)v[2]; h[3] = (_Float16)v[3];
        dst[tid + i * 256] = h;
    }
    for (int o = 32; o > 0; o >>= 1) s += __shfl_down(s, o);
    __shared__ float wsum[4];
    if ((tid & 63) == 0) wsum[tid >> 6] = s;
    __syncthreads();
    if (tid == 0) y2[row] = (wsum[0] + wsum[1]) + (wsum[2] + wsum[3]);
}

// ---------------- GEMM1: logits = c_cross*(x@imghT) - c_y2*y2 ----------------
// v6: B via glds (m97 path, proven); A from xhf fragment layout (coalesced,
// L2-resident 1.5MB). Alds deleted: 8 LDS instr/iter total.
__global__ __launch_bounds__(256, 3) void k_gemm1(
        const _Float16* __restrict__ xhf, const _Float16* __restrict__ imgh,
        const float* __restrict__ y2g, const float* __restrict__ sc,
        float* __restrict__ logits) {
    __shared__ _Float16 Blds[BN * BK];   // 16 KB, [row][g^(row&7)] 16B granules

    const int tid = threadIdx.x;
    const int wid = tid >> 6, lane = tid & 63;
    const int flat = blockIdx.x;          // 0..783
    const int xcd = flat & 7, loc = flat >> 3;          // loc 0..97
    const int m0 = (loc & 1) * BM;
    const int n0 = (xcd * 49 + (loc >> 1)) * BN;

    const _Float16* gB[4]; _Float16* lB[4];
    #pragma unroll
    for (int j = 0; j < 4; j++) {
        int seg = wid * 4 + j;
        int row = seg * 8 + (lane >> 3);
        int off = (((lane & 7) ^ (row & 7)) << 3);   // f16 elements
        gB[j] = imgh + (size_t)(n0 + row) * CHW + off;   // n0+row < NPAD (zero pad)
        lB[j] = Blds + seg * 512;
    }

    const int wm = wid >> 1, wn = wid & 1;
    const int rm = wm * 64, cn = wn * 64;
    const int lr = lane & 31, hi = lane >> 5;
    const int xm = (lr & 7) << 4;                    // read-side byte XOR
    const char* Bb = (const char*)Blds;
    const int br0 = (cn + lr) * 128,      br1 = (cn + 32 + lr) * 128;
    const int kof = hi * 16;

    // A-fragment bases (xhf): granule gi = it*8 + ks*2 + hi
    const int rowgrp0 = (m0 + rm) >> 5;              // rb=0 group; rb=1 -> +1
    const _Float16* aF0 = xhf + (size_t)rowgrp0 * XG * 256 + (size_t)hi * 256 + lr * 8;
    const _Float16* aF1 = aF0 + (size_t)XG * 256;

    f32x16 acc[2][2];
    #pragma unroll
    for (int mi = 0; mi < 2; mi++)
        #pragma unroll
        for (int ni = 0; ni < 2; ni++)
            #pragma unroll
            for (int r = 0; r < 16; r++) acc[mi][ni][r] = 0.f;

    for (int it = 0; it < CHW / BK; ++it) {
        if (it) __syncthreads();
        #pragma unroll
        for (int j = 0; j < 4; j++) glds16(gB[j] + it * BK, lB[j]);
        f16x8 a0[4], a1[4];
        #pragma unroll
        for (int ks = 0; ks < 4; ++ks) {             // coalesced L2-hot loads
            size_t o = ((size_t)it * 8 + ks * 2) * 256;
            a0[ks] = *(const f16x8*)(aF0 + o);
            a1[ks] = *(const f16x8*)(aF1 + o);
        }
        __syncthreads();
        #pragma unroll
        for (int ks = 0; ks < 4; ++ks) {
            int off = (ks * 32 + kof) ^ xm;
            f16x8 b0 = *(const f16x8*)(Bb + br0 + off);
            f16x8 b1 = *(const f16x8*)(Bb + br1 + off);
            acc[0][0] = __builtin_amdgcn_mfma_f32_32x32x16_f16(a0[ks], b0, acc[0][0], 0, 0, 0);
            acc[0][1] = __builtin_amdgcn_mfma_f32_32x32x16_f16(a0[ks], b1, acc[0][1], 0, 0, 0);
            acc[1][0] = __builtin_amdgcn_mfma_f32_32x32x16_f16(a1[ks], b0, acc[1][0], 0, 0, 0);
            acc[1][1] = __builtin_amdgcn_mfma_f32_32x32x16_f16(a1[ks], b1, acc[1][1], 0, 0, 0);
        }
    }

    const float c_cross = sc[2], c_y2 = sc[3];
    #pragma unroll
    for (int mi = 0; mi < 2; mi++)
        #pragma unroll
        for (int ni = 0; ni < 2; ni++) {
            int col = n0 + cn + ni * 32 + lr;
            if (col >= N_IMG) continue;
            float y2v = y2g[col];
            f32x16 v = acc[mi][ni];
            #pragma unroll
            for (int r = 0; r < 16; r++) {
                int row = m0 + rm + mi * 32 + (r & 3) + 8 * (r >> 2) + 4 * hi;
                logits[(size_t)row * N_IMG + col] = c_cross * v[r] - c_y2 * y2v;
            }
        }
}

// ---------------- fused row max + exp + row sum; writes ehf fragment layout ------
// ehf elem addr: ((rowgrp*EG + g)*32 + lr)*8; granules >= 6250 are zeros.
__global__ void k_softmax(const float* __restrict__ logits, _Float16* __restrict__ ehf,
                          float* __restrict__ rowsum) {
    int row = blockIdx.x, tid = threadIdx.x;
    const f32x4* lr4 = (const f32x4*)(logits + (size_t)row * N_IMG);
    __shared__ float wred[4];

    float m = -3.0e38f;
    for (int i = tid; i < N_IMG / 4; i += 256) {
        f32x4 v = lr4[i];
        m = fmaxf(m, fmaxf(fmaxf(v[0], v[1]), fmaxf(v[2], v[3])));
    }
    for (int o = 32; o > 0; o >>= 1) m = fmaxf(m, __shfl_down(m, o));
    if ((tid & 63) == 0) wred[tid >> 6] = m;
    __syncthreads();
    m = fmaxf(fmaxf(wred[0], wred[1]), fmaxf(wred[2], wred[3]));
    __syncthreads();

    const int rowgrp = row >> 5, lrr = row & 31;
    _Float16* base = ehf + ((size_t)rowgrp * EG * 32 + lrr) * 8;
    const f16x8 hz = {(_Float16)0.f,(_Float16)0.f,(_Float16)0.f,(_Float16)0.f,
                      (_Float16)0.f,(_Float16)0.f,(_Float16)0.f,(_Float16)0.f};
    float s = 0.f;
    for (int g = tid; g < EG; g += 256) {
        f16x8 h = hz;
        if (g < N_IMG / 8) {
            f32x4 v0 = lr4[g * 2], v1 = lr4[g * 2 + 1];
            float e0 = __expf(v0[0]-m), e1 = __expf(v0[1]-m);
            float e2 = __expf(v0[2]-m), e3 = __expf(v0[3]-m);
            float e4 = __expf(v1[0]-m), e5 = __expf(v1[1]-m);
            float e6 = __expf(v1[2]-m), e7 = __expf(v1[3]-m);
            s += ((e0+e1)+(e2+e3)) + ((e4+e5)+(e6+e7));
            h[0]=(_Float16)e0; h[1]=(_Float16)e1; h[2]=(_Float16)e2; h[3]=(_Float16)e3;
            h[4]=(_Float16)e4; h[5]=(_Float16)e5; h[6]=(_Float16)e6; h[7]=(_Float16)e7;
        }
        *(f16x8*)(base + (size_t)g * 256) = h;
    }
    for (int o = 32; o > 0; o >>= 1) s += __shfl_down(s, o);
    if ((tid & 63) == 0) wred[tid >> 6] = s;
    __syncthreads();
    if (tid == 0) rowsum[row] = (wred[0] + wred[1]) + (wred[2] + wred[3]);
}

// ---------------- GEMM2: partial[ck] = eh[:,chunk] @ imgh[chunk,:] ----------------
// v6: B via glds->Tmp->in-LDS transpose->Blds (R10 proven); A from ehf fragment
// layout (coalesced, L2-hot per XCD). Alds deleted: 20 LDS instr/iter.
__global__ __launch_bounds__(256, 3) void k_gemm2(
        const _Float16* __restrict__ ehf, const _Float16* __restrict__ imgh,
        float* __restrict__ partial) {
    __shared__ _Float16 Blds[BN * BK];     // 16 KB, [d][k] swizzled granules
    __shared__ _Float16 Tmp[BK * BN];      // 16 KB, [k][d] linear

    const int tid = threadIdx.x;
    const int wid = tid >> 6, lane = tid & 63;
    const int flat = blockIdx.x;          // 0..767
    const int xcd = flat & 7, loc = flat >> 3;          // loc 0..95
    const int ck  = xcd * 2 + (loc >= 48 ? 1 : 0);
    const int rem = loc - (loc >= 48 ? 48 : 0);         // 0..47
    const int m0 = (rem & 1) * BM;
    const int d0 = (rem >> 1) * BN;
    const int kbase = ck * KCHUNK;
    const int ITERS = KCHUNK / BK;        // 49

    const _Float16* gB[4]; _Float16* lB[4];
    #pragma unroll
    for (int j = 0; j < 4; j++) {
        int seg = wid * 4 + j;                         // 0..15
        gB[j] = imgh + (size_t)(kbase + seg * 4 + (lane >> 4)) * CHW + d0 + (lane & 15) * 8;
        lB[j] = Tmp + seg * 512;
    }

    const int q   = tid & 31;             // d-quad 0..31
    const int oct = tid >> 5;             // k-octet 0..7

    const int wm = wid >> 1, wn = wid & 1;
    const int rm = wm * 64, cn = wn * 64;
    const int lr = lane & 31, hi = lane >> 5;
    const int xm = (lr & 7) << 4;
    const int br0 = (cn + lr) * 128, br1 = (cn + 32 + lr) * 128;
    const int kof = hi * 16;
    const char* Bb = (const char*)Blds;

    // A-fragment bases (ehf): granule g = (kbase>>3) + it*8 + ks*2 + hi
    const int rowgrp0 = (m0 + rm) >> 5;
    const _Float16* aF0 = ehf + (size_t)rowgrp0 * EG * 256
                        + ((size_t)(kbase >> 3) + hi) * 256 + lr * 8;
    const _Float16* aF1 = aF0 + (size_t)EG * 256;

    f32x16 acc[2][2];
    #pragma unroll
    for (int mi = 0; mi < 2; mi++)
        #pragma unroll
        for (int ni = 0; ni < 2; ni++)
            #pragma unroll
            for (int r = 0; r < 16; r++) acc[mi][ni][r] = 0.f;

    // prologue: stage it=0 into Tmp
    #pragma unroll
    for (int j = 0; j < 4; j++) glds16(gB[j], lB[j]);

    for (int it = 0; it < ITERS; ++it) {
        __syncthreads();   // Tmp(it) landed; Blds(it-1) consumed

        // A-fragments (coalesced; drain at next barrier, hidden under transpose)
        f16x8 afr0[4], afr1[4];
        #pragma unroll
        for (int ks = 0; ks < 4; ++ks) {
            size_t o = ((size_t)it * 8 + ks * 2) * 256;
            afr0[ks] = *(const f16x8*)(aF0 + o);
            afr1[ks] = *(const f16x8*)(aF1 + o);
        }
        // transpose Tmp[k][d] -> Blds[d][k] (swizzled)
        {
            f16x4 r[8];
            #pragma unroll
            for (int j = 0; j < 8; j++)
                r[j] = *(const f16x4*)&Tmp[(oct * 8 + j) * 128 + q * 4];
            #pragma unroll
            for (int dd = 0; dd < 4; dd++) {
                f16x8 w;
                #pragma unroll
                for (int j = 0; j < 8; j++) w[j] = r[j][dd];
                int d = q * 4 + dd;
                *(f16x8*)((char*)Blds + d * 128 + ((oct ^ (d & 7)) << 4)) = w;
            }
        }
        __syncthreads();   // Blds ready; Tmp free; A-frags drained

        if (it + 1 < ITERS) {
            #pragma unroll
            for (int j = 0; j < 4; j++) glds16(gB[j] + (size_t)(it + 1) * BK * CHW, lB[j]);
        }
        #pragma unroll
        for (int ks = 0; ks < 4; ++ks) {
            int offb = (ks * 32 + kof) ^ xm;
            f16x8 b0 = *(const f16x8*)(Bb + br0 + offb);
            f16x8 b1 = *(const f16x8*)(Bb + br1 + offb);
            acc[0][0] = __builtin_amdgcn_mfma_f32_32x32x16_f16(afr0[ks], b0, acc[0][0], 0, 0, 0);
            acc[0][1] = __builtin_amdgcn_mfma_f32_32x32x16_f16(afr0[ks], b1, acc[0][1], 0, 0, 0);
            acc[1][0] = __builtin_amdgcn_mfma_f32_32x32x16_f16(afr1[ks], b0, acc[1][0], 0, 0, 0);
            acc[1][1] = __builtin_amdgcn_mfma_f32_32x32x16_f16(afr1[ks], b1, acc[1][1], 0, 0, 0);
        }
    }

    float* pp = partial + (size_t)ck * BROWS * CHW;
    #pragma unroll
    for (int mi = 0; mi < 2; mi++)
        #pragma unroll
        for (int ni = 0; ni < 2; ni++) {
            int dcol = d0 + cn + ni * 32 + lr;
            f32x16 v = acc[mi][ni];
            #pragma unroll
            for (int r = 0; r < 16; r++) {
                int row = m0 + rm + mi * 32 + (r & 3) + 8 * (r >> 2) + 4 * hi;
                pp[(size_t)row * CHW + dcol] = v[r];
            }
        }
}

// ---------------- reduce partials + final score ----------------
__global__ void k_final(const float* __restrict__ partial, const float* __restrict__ x,
                        const float* __restrict__ rowsum, const float* __restrict__ sc,
                        float* __restrict__ out) {
    int idx = blockIdx.x * 256 + threadIdx.x;
    int row = idx / (CHW / 4);
    float at = sc[0], invbt2 = sc[4];
    float scale = at * invbt2 / rowsum[row];
    const f32x4* p4 = (const f32x4*)partial;
    f32x4 s = p4[idx];
    #pragma unroll
    for (int c = 1; c < NSPLIT; c++) s = s + p4[(size_t)c * (BROWS * CHW / 4) + idx];
    f32x4 xv = ((const f32x4*)x)[idx];
    f32x4 o;
    #pragma unroll
    for (int j = 0; j < 4; j++) o[j] = s[j] * scale - xv[j] * invbt2;
    ((f32x4*)out)[idx] = o;
}

extern "C" void kernel_launch(void* const* d_in, const int* in_sizes, int n_in,
                              void* d_out, int out_size, void* d_ws, size_t ws_size,
                              hipStream_t stream) {
    const float* t   = (const float*)d_in[0];
    const float* x   = (const float*)d_in[1];
    const float* img = (const float*)d_in[2];
    float* out = (float*)d_out;
    char* ws = (char*)d_ws;

    // ws layout (bytes)
    float*    sc     = (float*)(ws + 0);                   // 64 B
    float*    rowsum = (float*)(ws + 256);                 // 1 KB
    float*    y2     = (float*)(ws + 4096);                // 200 KB
    _Float16* xhf    = (_Float16*)(ws + 212992);           // 1.5 MB  fragment layout
    _Float16* imgh   = (_Float16*)(ws + 2097152);          // 308.3 MB [NPAD][CHW]
    _Float16* ehf    = (_Float16*)(ws + 310378496);        // 25.7 MB fragment layout
    float*    logits = (float*)(ws + 336068608);           // 51.2 MB
    float*    partial = logits;                            // reused (50.4 MB)

    k_scalars<<<1, 64, 0, stream>>>(t, sc);
    k_xprep<<<BROWS, 128, 0, stream>>>(x, xhf);
    k_prep<<<NPAD, 256, 0, stream>>>(img, imgh, y2);
    k_gemm1<<<784, 256, 0, stream>>>(xhf, imgh, y2, sc, logits);
    k_softmax<<<256, 256, 0, stream>>>(logits, ehf, rowsum);
    k_gemm2<<<768, 256, 0, stream>>>(ehf, imgh, partial);
    k_final<<<(BROWS * CHW / 4) / 256, 256, 0, stream>>>(partial, x, rowsum, sc, out);
}